// Round 8
// baseline (155.631 us; speedup 1.0000x reference)
//
#include <hip/hip_runtime.h>

typedef _Float16 half8 __attribute__((ext_vector_type(8)));
typedef float    f32x16 __attribute__((ext_vector_type(16)));

constexpr int kH = 16;    // heads
constexpr int kO = 1024;  // codebook options
constexpr int kA = 128;   // head size
constexpr int kBS = 4096; // B*S positions
constexpr int MTILE = 64; // positions per block
constexpr int NITER = 16; // option-tiles (32 options) per wave

typedef const __attribute__((address_space(1))) uint32_t* gas_ptr;
typedef __attribute__((address_space(3))) uint32_t* las_ptr;

// ---- Pass 1: split W into fp16 hi/lo planes, packed fragment-major ----
// Packed (halfs): (h*32 + t)*8192 + plane*4096 + ks*512 + lane*8 + j
// LDS-transpose version: block = one 32-option tile; coalesced 16B reads AND writes.
__global__ void split_w(const float* __restrict__ w, ushort* __restrict__ wp) {
    __shared__ float lds[32 * 132];   // 32 rows x 128, +4 pad vs bank aliasing
    const int tid = threadIdx.x;
    const int b   = blockIdx.x;       // b = h*32 + t
    const float* src = w + (size_t)b * 4096;   // rows [t*32, t*32+32) of head h

    {   // load phase: 256 thr x 16 floats, fully coalesced
        int r = tid >> 3, a0 = (tid & 7) * 16;
        const float* s = src + r * kA + a0;
        float* d = lds + r * 132 + a0;
        *(float4*)(d)      = *(const float4*)(s);
        *(float4*)(d + 4)  = *(const float4*)(s + 4);
        *(float4*)(d + 8)  = *(const float4*)(s + 8);
        *(float4*)(d + 12) = *(const float4*)(s + 12);
    }
    __syncthreads();

    // convert phase: thread (ks = tid>>5, m = tid&31) produces fragment halfs
    // for lanes {2m, 2m+1} at k-step ks -> 16 contiguous hi halfs + 16 lo halfs.
    const int ks = tid >> 5, m = tid & 31;
    ushort hi[16], lo[16];
#pragma unroll
    for (int e = 0; e < 2; ++e) {
        int L = 2 * m + e;
        int half = L >> 5, o31 = L & 31;
        const float* s = lds + o31 * 132 + ks * 16 + half * 8;
#pragma unroll
        for (int j = 0; j < 8; ++j) {
            float v = s[j];
            _Float16 hj = (_Float16)v;
            hi[e * 8 + j] = __builtin_bit_cast(ushort, hj);
            lo[e * 8 + j] = __builtin_bit_cast(ushort, (_Float16)(v - (float)hj));
        }
    }
    ushort* dst = wp + (size_t)b * 8192 + ks * 512 + m * 16;  // plane 0 (hi)
    *(uint4*)(dst)          = *(uint4*)(hi);
    *(uint4*)(dst + 8)      = *(uint4*)(hi + 8);
    *(uint4*)(dst + 4096)     = *(uint4*)(lo);               // plane 1 (lo)
    *(uint4*)(dst + 4096 + 8) = *(uint4*)(lo + 8);
}

// ---- Pass 2: LDS double-buffered logits (fp16-split, fp32 accum) + argmax + gather ----
// 3 INDEPENDENT accumulator chains (wh*xh | wh*xl | wl*xh) interleaved per-ks:
// dependency distance 3 MFMAs, chain depth 8 -> breaks the serial-latency wall.
__launch_bounds__(256, 2)
__global__ void vq_argmax_gather(const float* __restrict__ x,
                                 const ushort* __restrict__ wp,
                                 const float* __restrict__ cb,
                                 float* __restrict__ out) {
    __shared__ ushort wtile[2][2][8192];  // [buf][nhalf][plane*4096 + ks*512 + lane*8]
    __shared__ float red_max[2][MTILE];
    __shared__ int   red_idx[2][MTILE];

    const int tid   = threadIdx.x;
    const int lane  = tid & 63;
    const int wv    = tid >> 6;
    const int nhalf = wv >> 1;
    const int mtile = wv & 1;
    const int bid   = blockIdx.x;
    // XCD-aware: XCD (bid&7) touches only heads {2x,2x+1} -> W+cb L2-resident
    const int h  = ((bid & 7) << 1) | ((bid >> 3) & 1);
    const int p0 = (bid >> 4) * MTILE;

    const int l31  = lane & 31;
    const int half = lane >> 5;

    const ushort* wh_base = wp + h * 32 * 8192;   // this head's packed W

    // DMA: 32 chunks/iter (2 nhalf x 2 plane x 8 ks), 8 per wave.
    auto stage = [&](int it, int buf) {
#pragma unroll
        for (int q = 0; q < 8; ++q) {
            int c   = wv * 8 + q;
            int nh  = c >> 4, rem = c & 15;
            const ushort* g = wh_base + (nh * 16 + it) * 8192 + rem * 512 + lane * 8;
            ushort* l = &wtile[buf][nh][rem * 512];
            __builtin_amdgcn_global_load_lds((gas_ptr)(const void*)g,
                                             (las_ptr)(void*)l, 16, 0, 0);
        }
    };

    stage(0, 0);   // tile-0 DMA in flight under the x load/convert phase

    // stationary x fragments (fp32 -> fp16 hi/lo in-register)
    const int mrow = p0 + mtile * 32 + l31;
    const float* xbase = x + (mrow * kH + h) * kA + half * 8;
    half8 xh[8], xl[8];
#pragma unroll
    for (int ks = 0; ks < 8; ++ks) {
        float4 v0 = *(const float4*)(xbase + ks * 16);
        float4 v1 = *(const float4*)(xbase + ks * 16 + 4);
        float va[8] = { v0.x, v0.y, v0.z, v0.w, v1.x, v1.y, v1.z, v1.w };
        half8 hi, lo;
#pragma unroll
        for (int j = 0; j < 8; ++j) {
            _Float16 hj = (_Float16)va[j];
            hi[j] = hj;
            lo[j] = (_Float16)(va[j] - (float)hj);
        }
        xh[ks] = hi; xl[ks] = lo;
    }

    float best = -1e30f;
    int   bidx = 0;
    const int nwb = nhalf * (kO / 2);

    __syncthreads();   // tile 0 staged

    for (int it = 0; it < NITER; ++it) {
        const int cur = it & 1;
        if (it + 1 < NITER) stage(it + 1, cur ^ 1);   // async into other buffer

        const ushort* lbase = &wtile[cur][nhalf][lane * 8];
        half8 wh[8], wl[8];
#pragma unroll
        for (int ks = 0; ks < 8; ++ks) {
            wh[ks] = *(const half8*)(lbase + ks * 512);          // ds_read_b128
            wl[ks] = *(const half8*)(lbase + 4096 + ks * 512);
        }
        f32x16 a1 = {}, a2 = {}, a3 = {};   // 3 independent chains
#pragma unroll
        for (int ks = 0; ks < 8; ++ks) {
            a1 = __builtin_amdgcn_mfma_f32_32x32x16_f16(wh[ks], xh[ks], a1, 0, 0, 0);
            a2 = __builtin_amdgcn_mfma_f32_32x32x16_f16(wh[ks], xl[ks], a2, 0, 0, 0);
            a3 = __builtin_amdgcn_mfma_f32_32x32x16_f16(wl[ks], xh[ks], a3, 0, 0, 0);
        }

        // fold 16 option-rows into running scalar argmax (rows ascend with r)
        float lv = a1[0] + a2[0] + a3[0];
        int   lr = 0;
#pragma unroll
        for (int r = 1; r < 16; ++r) {
            float v = a1[r] + a2[r] + a3[r];
            if (v > lv) { lv = v; lr = r; }             // strict >: earliest row wins
        }
        int li = nwb + it * 32 + 4 * half + (lr & 3) + 8 * (lr >> 2);
        if (lv > best) { best = lv; bidx = li; }        // strict >: earlier tile wins

        __syncthreads();   // readers done with buf[cur] + next DMAs landed
    }

    // merge lane halves (disjoint option rows, same position column)
    {
        float om = __shfl_xor(best, 32, 64);
        int   oi = __shfl_xor(bidx, 32, 64);
        if (om > best || (om == best && oi < bidx)) { best = om; bidx = oi; }
    }
    if (half == 0) {
        red_max[nhalf][mtile * 32 + l31] = best;
        red_idx[nhalf][mtile * 32 + l31] = bidx;
    }
    __syncthreads();

    // gather: out[p0+row, h, :] = cb[h, argmax, :]
    for (int i = tid; i < MTILE * 32; i += 256) {
        int row = i >> 5, ch = i & 31;
        float m0 = red_max[0][row], m1 = red_max[1][row];
        int o = (m1 > m0) ? red_idx[1][row] : red_idx[0][row]; // ties -> smaller o
        float4 v = *(const float4*)(cb + (h * kO + o) * kA + ch * 4);
        *(float4*)(out + ((p0 + row) * kH + h) * kA + ch * 4) = v;
    }
}

extern "C" void kernel_launch(void* const* d_in, const int* in_sizes, int n_in,
                              void* d_out, int out_size, void* d_ws, size_t ws_size,
                              hipStream_t stream) {
    const float* x  = (const float*)d_in[0];   // [4096,16,128] fp32
    const float* w  = (const float*)d_in[1];   // [16,1024,128] fp32
    const float* cb = (const float*)d_in[2];   // [16,1024,128] fp32
    // d_in[3] = temperature: forward value is temperature-independent
    float* out = (float*)d_out;                // [4096,16,128] fp32

    ushort* wpacked = (ushort*)d_ws;           // 8 MiB packed hi+lo planes

    split_w<<<dim3(kH * 32), dim3(256), 0, stream>>>(w, wpacked);
    vq_argmax_gather<<<dim3((kBS / MTILE) * kH), dim3(256), 0, stream>>>(x, wpacked, cb, out);
}